// Round 3
// baseline (159.419 us; speedup 1.0000x reference)
//
#include <hip/hip_runtime.h>

// VIN on one CU. R3: the VI loop body contains ZERO global/scalar loads —
// all 72 Wq[:,1] weights live in thread-private VGPRs (512 thr -> 2 waves/SIMD
// -> 256 VGPR cap). Own-row v kept in registers; only top/bottom rows come
// from LDS. X staged through LDS so the zero halo replaces boundary predication.

#define ACT 8
#define HID 150
#define STR 76   // row stride in floats; 76 mod 32 = 12 -> uniform b128 bank starts

typedef float v2f __attribute__((ext_vector_type(2)));

__device__ __forceinline__ v2f pkfma(float w, v2f b, v2f c) {
  return __builtin_elementwise_fma((v2f){w, w}, b, c);
}
__device__ __forceinline__ v2f pkmax(v2f a, v2f b) {
  return __builtin_elementwise_max(a, b);
}

struct Win { v2f p[9]; };  // overlapping pairs of a 10-wide window

__device__ __forceinline__ Win mkwin(const float* rowp, int colb) {
  Win W;
  const float  eL = rowp[colb + 3];
  const float4 a  = *(const float4*)(rowp + colb + 4);
  const float4 b  = *(const float4*)(rowp + colb + 8);
  const float  eR = rowp[colb + 12];
  W.p[0] = (v2f){eL, a.x};   W.p[1] = (v2f){a.x, a.y};
  W.p[2] = (v2f){a.y, a.z};  W.p[3] = (v2f){a.z, a.w};
  W.p[4] = (v2f){a.w, b.x};  W.p[5] = (v2f){b.x, b.y};
  W.p[6] = (v2f){b.y, b.z};  W.p[7] = (v2f){b.z, b.w};
  W.p[8] = (v2f){b.w, eR};
  return W;
}

__device__ __forceinline__ Win mkwin_reg(const v2f (&v)[4], float eL, float eR) {
  Win W;
  W.p[0] = (v2f){eL, v[0].x};     W.p[1] = v[0];
  W.p[2] = (v2f){v[0].y, v[1].x}; W.p[3] = v[1];
  W.p[4] = (v2f){v[1].y, v[2].x}; W.p[5] = v[2];
  W.p[6] = (v2f){v[2].y, v[3].x}; W.p[7] = v[3];
  W.p[8] = (v2f){v[3].y, eR};
  return W;
}

__device__ __forceinline__ void vi_step(const float (*src)[STR], float (*dst)[STR],
                                        v2f (&vreg)[4],
                                        const v2f (&qr)[ACT][4],
                                        const float (&wq1)[72],
                                        int row, int colb) {
  Win T = mkwin(&src[row][0], colb);
  Win B = mkwin(&src[row + 2][0], colb);
  const float eL = src[row + 1][colb + 3];
  const float eR = src[row + 1][colb + 12];
  Win M = mkwin_reg(vreg, eL, eR);

  v2f mx[4];
  #pragma unroll
  for (int a = 0; a < ACT; ++a) {
    v2f q[4] = {qr[a][0], qr[a][1], qr[a][2], qr[a][3]};
    #pragma unroll
    for (int dx = 0; dx < 3; ++dx) {
      const float wt = wq1[a * 9 + dx];
      const float wm = wq1[a * 9 + 3 + dx];
      const float wb = wq1[a * 9 + 6 + dx];
      #pragma unroll
      for (int j = 0; j < 4; ++j) {
        q[j] = pkfma(wt, T.p[2 * j + dx], q[j]);
        q[j] = pkfma(wm, M.p[2 * j + dx], q[j]);
        q[j] = pkfma(wb, B.p[2 * j + dx], q[j]);
      }
    }
    #pragma unroll
    for (int j = 0; j < 4; ++j) mx[j] = a ? pkmax(mx[j], q[j]) : q[j];
  }
  #pragma unroll
  for (int j = 0; j < 4; ++j) vreg[j] = mx[j];
  *(float4*)&dst[row + 1][colb + 4] = make_float4(mx[0].x, mx[0].y, mx[1].x, mx[1].y);
  *(float4*)&dst[row + 1][colb + 8] = make_float4(mx[2].x, mx[2].y, mx[3].x, mx[3].y);
  __syncthreads();
}

__launch_bounds__(512, 2)
__global__ void vin_kernel(const float* __restrict__ X,
                           const int*   __restrict__ S1,
                           const int*   __restrict__ S2,
                           const float* __restrict__ Wh,
                           const float* __restrict__ bh,
                           const float* __restrict__ Wr,
                           const float* __restrict__ Wq,
                           float*       __restrict__ out) {
  __shared__ float r_s[66][STR];
  __shared__ float v_s[2][66][STR];
  __shared__ float weff_s[19];

  const int tid  = threadIdx.x;
  const int row  = tid >> 3;         // 0..63 (also k for stage 4)
  const int colb = (tid & 7) << 3;   // 0,8,...,56

  // prefetch query coords: HBM latency hides behind everything else
  const int qy = S1[row];
  const int qx = S2[row];

  // ---- zero LDS (halo ring must be 0) ----
  {
    const float4 z = make_float4(0.f, 0.f, 0.f, 0.f);
    float4* r4 = (float4*)&r_s[0][0];
    for (int i = tid; i < 66 * STR / 4; i += 512) r4[i] = z;
    float4* v4 = (float4*)&v_s[0][0][0];
    for (int i = tid; i < 2 * 66 * STR / 4; i += 512) v4[i] = z;
  }
  __syncthreads();

  // ---- stage X[0] into v_s interiors (ch0 -> v_s[0], ch1 -> v_s[1]) ----
  #pragma unroll
  for (int c = 0; c < 2; ++c)
    #pragma unroll
    for (int j = 0; j < 2; ++j) {
      const int g = tid * 8 + j * 4;
      const int y = g >> 6, x = g & 63;
      *(float4*)&v_s[c][y + 1][x + 4] = *(const float4*)&X[c * 4096 + g];
    }
  // ---- weff contraction, 152 threads (19 outputs x 8 partials + shfl reduce) ----
  if (tid < 152) {
    const int t = tid >> 3, part = tid & 7;
    float acc = 0.f;
    for (int h = part; h < HID; h += 8)
      acc += Wr[h] * (t < 18 ? Wh[h * 18 + t] : bh[h]);
    acc += __shfl_xor(acc, 1);
    acc += __shfl_xor(acc, 2);
    acc += __shfl_xor(acc, 4);
    if (part == 0) weff_s[t] = acc;
  }
  __syncthreads();

  // ---- stage 1: r = conv3x3(X, Weff) + beff (no predication: halo is 0) ----
  {
    float wl[18];
    #pragma unroll
    for (int t = 0; t < 18; ++t) wl[t] = weff_s[t];
    const float beff = weff_s[18];
    v2f acc[4];
    #pragma unroll
    for (int j = 0; j < 4; ++j) acc[j] = (v2f){beff, beff};
    #pragma unroll
    for (int c = 0; c < 2; ++c)
      #pragma unroll
      for (int dy = 0; dy < 3; ++dy) {
        Win W = mkwin(&v_s[c][row + dy][0], colb);
        #pragma unroll
        for (int dx = 0; dx < 3; ++dx) {
          const float w = wl[c * 9 + dy * 3 + dx];
          #pragma unroll
          for (int j = 0; j < 4; ++j) acc[j] = pkfma(w, W.p[2 * j + dx], acc[j]);
        }
      }
    *(float4*)&r_s[row + 1][colb + 4] = make_float4(acc[0].x, acc[0].y, acc[1].x, acc[1].y);
    *(float4*)&r_s[row + 1][colb + 8] = make_float4(acc[2].x, acc[2].y, acc[3].x, acc[3].y);
  }
  __syncthreads();

  // ---- stage 2: qr = conv3x3(r, Wq[:,0]) (iteration-invariant); v1 = max_a qr ----
  v2f qr[ACT][4];
  v2f vreg[4];
  {
    Win R[3];
    #pragma unroll
    for (int dy = 0; dy < 3; ++dy) R[dy] = mkwin(&r_s[row + dy][0], colb);
    #pragma unroll
    for (int a = 0; a < ACT; ++a) {
      v2f q[4];
      #pragma unroll
      for (int j = 0; j < 4; ++j) q[j] = (v2f){0.f, 0.f};
      #pragma unroll
      for (int dy = 0; dy < 3; ++dy)
        #pragma unroll
        for (int dx = 0; dx < 3; ++dx) {
          const float w = Wq[a * 18 + dy * 3 + dx];
          #pragma unroll
          for (int j = 0; j < 4; ++j) q[j] = pkfma(w, R[dy].p[2 * j + dx], q[j]);
        }
      #pragma unroll
      for (int j = 0; j < 4; ++j) {
        qr[a][j] = q[j];
        vreg[j] = a ? pkmax(vreg[j], q[j]) : q[j];
      }
    }
    *(float4*)&v_s[0][row + 1][colb + 4] = make_float4(vreg[0].x, vreg[0].y, vreg[1].x, vreg[1].y);
    *(float4*)&v_s[0][row + 1][colb + 8] = make_float4(vreg[2].x, vreg[2].y, vreg[3].x, vreg[3].y);
  }

  // ---- hoist ALL stage-3 weights into thread-private VGPRs, once ----
  float wq1[72];
  #pragma unroll
  for (int a = 0; a < ACT; ++a)
    #pragma unroll
    for (int t = 0; t < 9; ++t) wq1[a * 9 + t] = Wq[a * 18 + 9 + t];
  __syncthreads();

  // ---- stage 3: 18 VI updates, ping-pong, zero loads besides v-neighborhood ----
  for (int it = 0; it < 9; ++it) {
    vi_step(v_s[0], v_s[1], vreg, qr, wq1, row, colb);
    vi_step(v_s[1], v_s[0], vreg, qr, wq1, row, colb);
  }
  // v19 in v_s[0]

  // ---- stage 4: q20 at query points + softmax over ACT (512 = NK*ACT threads) ----
  {
    const int a = tid & 7;
    float accq = 0.f;
    #pragma unroll
    for (int dy = 0; dy < 3; ++dy)
      #pragma unroll
      for (int dx = 0; dx < 3; ++dx) {
        const float w0 = Wq[a * 18 + dy * 3 + dx];
        accq += w0 * r_s[qy + dy][qx + dx + 3];
        accq += wq1[a * 9 + dy * 3 + dx] * v_s[0][qy + dy][qx + dx + 3];
      }
    float m = accq;
    m = fmaxf(m, __shfl_xor(m, 1));
    m = fmaxf(m, __shfl_xor(m, 2));
    m = fmaxf(m, __shfl_xor(m, 4));
    const float e = __expf(accq - m);
    float s = e;
    s += __shfl_xor(s, 1);
    s += __shfl_xor(s, 2);
    s += __shfl_xor(s, 4);
    out[tid] = e / s;
  }
}

extern "C" void kernel_launch(void* const* d_in, const int* in_sizes, int n_in,
                              void* d_out, int out_size, void* d_ws, size_t ws_size,
                              hipStream_t stream) {
  const float* X  = (const float*)d_in[0];
  const int*   S1 = (const int*)d_in[1];
  const int*   S2 = (const int*)d_in[2];
  const float* Wh = (const float*)d_in[3];
  const float* bh = (const float*)d_in[4];
  const float* Wr = (const float*)d_in[5];
  const float* Wq = (const float*)d_in[6];
  float* out = (float*)d_out;

  vin_kernel<<<1, 512, 0, stream>>>(X, S1, S2, Wh, bh, Wr, Wq, out);
}

// Round 5
// 119.938 us; speedup vs baseline: 1.3292x; 1.3292x over previous
//
#include <hip/hip_runtime.h>

// VIN on one CU, 1024 threads (16 waves). R5 = R4 structure + stage-4 fix:
// readfirstlane (uload) is ONLY legal for wave-uniform addresses. Stage 4's
// action index a=tid&7 varies per lane -> plain loads there. Stage 2/3 weight
// pinning keeps uload (indices are unroll constants -> uniform).
//  - weff contraction: 19 outputs x 32 lanes, parallel loads + shfl reduce
//  - VI loop: ZERO memory ops besides the v tile (weights in SGPRs, qr in VGPRs)
//  - 4 cells/thread (R3's 8-cell shape spilled); 1 barrier/iter ping-pong

#define ACT 8
#define HID 150
#define STR 76   // row stride floats; (colb+4)*4 is 16B-aligned for b128

typedef float v2f __attribute__((ext_vector_type(2)));

__device__ __forceinline__ v2f pkfma(float w, v2f b, v2f c) {
  return __builtin_elementwise_fma((v2f){w, w}, b, c);
}
__device__ __forceinline__ v2f pkmax(v2f a, v2f b) {
  return __builtin_elementwise_max(a, b);
}
// Wave-uniform load -> SGPR. PRECONDITION: p identical across the wave.
__device__ __forceinline__ float uload(const float* p) {
  return __int_as_float(__builtin_amdgcn_readfirstlane(__float_as_int(*p)));
}

struct Win5 { v2f p[5]; };  // overlapping pairs over 6-wide window (4 cells)

__device__ __forceinline__ Win5 mkwin(const float* rowp, int colb) {
  Win5 W;
  const float  eL = rowp[colb + 3];
  const float4 a  = *(const float4*)(rowp + colb + 4);
  const float  eR = rowp[colb + 8];
  W.p[0] = (v2f){eL, a.x};  W.p[1] = (v2f){a.x, a.y};
  W.p[2] = (v2f){a.y, a.z}; W.p[3] = (v2f){a.z, a.w};
  W.p[4] = (v2f){a.w, eR};
  return W;
}

__launch_bounds__(1024, 4)
__global__ void vin_kernel(const float* __restrict__ X,
                           const int*   __restrict__ S1,
                           const int*   __restrict__ S2,
                           const float* __restrict__ Wh,
                           const float* __restrict__ bh,
                           const float* __restrict__ Wr,
                           const float* __restrict__ Wq,
                           float*       __restrict__ out) {
  __shared__ float r_s[66][STR];
  __shared__ float v_s[2][66][STR];
  __shared__ float weff_s[19];
  __shared__ int   s12_s[128];   // S1 | S2

  const int tid  = threadIdx.x;
  const int row  = tid >> 4;          // 0..63
  const int colb = (tid & 15) << 2;   // 0,4,...,60

  // ---- zero LDS (halo ring must stay 0) ----
  {
    const float4 z = make_float4(0.f, 0.f, 0.f, 0.f);
    float4* r4 = (float4*)&r_s[0][0];
    for (int i = tid; i < 66 * STR / 4; i += 1024) r4[i] = z;
    float4* v4 = (float4*)&v_s[0][0][0];
    for (int i = tid; i < 2 * 66 * STR / 4; i += 1024) v4[i] = z;
  }
  if (tid < 128) s12_s[tid] = (tid < 64) ? S1[tid] : S2[tid - 64];
  __syncthreads();

  // ---- stage X[0] into v_s interiors (ch0 -> v_s[0], ch1 -> v_s[1]) ----
  {
    const int g = tid << 2;            // 0..4092 step 4
    const int y = g >> 6, x = g & 63;
    *(float4*)&v_s[0][y + 1][x + 4] = *(const float4*)&X[g];
    *(float4*)&v_s[1][y + 1][x + 4] = *(const float4*)&X[4096 + g];
  }

  // ---- weff contraction: 19 outputs x 32 lanes, 5 parallel loads each ----
  if (tid < 19 * 32) {
    const int t = tid >> 5, lane = tid & 31;
    float acc = 0.f;
    #pragma unroll
    for (int i = 0; i < 5; ++i) {
      const int h = lane + 32 * i;
      if (h < HID) acc += Wr[h] * (t < 18 ? Wh[h * 18 + t] : bh[h]);
    }
    acc += __shfl_xor(acc, 1);
    acc += __shfl_xor(acc, 2);
    acc += __shfl_xor(acc, 4);
    acc += __shfl_xor(acc, 8);
    acc += __shfl_xor(acc, 16);
    if (lane == 0) weff_s[t] = acc;
  }
  __syncthreads();

  // ---- stage 1: r = conv3x3(X, Weff) + beff (halo-zero replaces predication) ----
  {
    float wl[18];
    #pragma unroll
    for (int t = 0; t < 18; ++t) wl[t] = weff_s[t];
    const float beff = weff_s[18];
    v2f acc0 = (v2f){beff, beff}, acc1 = (v2f){beff, beff};
    #pragma unroll
    for (int c = 0; c < 2; ++c)
      #pragma unroll
      for (int dy = 0; dy < 3; ++dy) {
        Win5 W = mkwin(&v_s[c][row + dy][0], colb);
        #pragma unroll
        for (int dx = 0; dx < 3; ++dx) {
          const float w = wl[c * 9 + dy * 3 + dx];
          acc0 = pkfma(w, W.p[dx], acc0);
          acc1 = pkfma(w, W.p[dx + 2], acc1);
        }
      }
    *(float4*)&r_s[row + 1][colb + 4] = make_float4(acc0.x, acc0.y, acc1.x, acc1.y);
  }
  __syncthreads();

  // ---- stage 2: qr = conv3x3(r, Wq[:,0]); v1 = max_a qr ----
  v2f qr[ACT][2];
  v2f vreg[2];
  {
    Win5 R[3];
    #pragma unroll
    for (int dy = 0; dy < 3; ++dy) R[dy] = mkwin(&r_s[row + dy][0], colb);
    #pragma unroll
    for (int a = 0; a < ACT; ++a) {
      v2f q0 = (v2f){0.f, 0.f}, q1 = (v2f){0.f, 0.f};
      #pragma unroll
      for (int dy = 0; dy < 3; ++dy)
        #pragma unroll
        for (int dx = 0; dx < 3; ++dx) {
          const float w = uload(&Wq[a * 18 + dy * 3 + dx]);  // uniform index
          q0 = pkfma(w, R[dy].p[dx], q0);
          q1 = pkfma(w, R[dy].p[dx + 2], q1);
        }
      qr[a][0] = q0; qr[a][1] = q1;
      vreg[0] = a ? pkmax(vreg[0], q0) : q0;
      vreg[1] = a ? pkmax(vreg[1], q1) : q1;
    }
    *(float4*)&v_s[0][row + 1][colb + 4] =
        make_float4(vreg[0].x, vreg[0].y, vreg[1].x, vreg[1].y);
  }

  // ---- pin all 72 VI-loop weights wave-uniform (SGPR file; indices uniform) ----
  float wq1[72];
  #pragma unroll
  for (int a = 0; a < ACT; ++a)
    #pragma unroll
    for (int t = 0; t < 9; ++t) wq1[a * 9 + t] = uload(&Wq[a * 18 + 9 + t]);
  __syncthreads();

  // ---- stage 3: 18 VI updates, ping-pong, zero memory ops except v tiles ----
  #pragma unroll 1
  for (int it = 0; it < 9; ++it) {
    #pragma unroll
    for (int half = 0; half < 2; ++half) {
      const float (*src)[STR] = v_s[half];
      float (*dst)[STR] = v_s[half ^ 1];

      Win5 T = mkwin(&src[row][0], colb);
      Win5 B = mkwin(&src[row + 2][0], colb);
      const float eL = src[row + 1][colb + 3];
      const float eR = src[row + 1][colb + 8];
      Win5 M;
      M.p[0] = (v2f){eL, vreg[0].x};        M.p[1] = vreg[0];
      M.p[2] = (v2f){vreg[0].y, vreg[1].x}; M.p[3] = vreg[1];
      M.p[4] = (v2f){vreg[1].y, eR};

      v2f m0, m1;
      #pragma unroll
      for (int a = 0; a < ACT; ++a) {
        v2f q0 = qr[a][0], q1 = qr[a][1];
        #pragma unroll
        for (int dx = 0; dx < 3; ++dx) {
          const float wt = wq1[a * 9 + dx];
          const float wm = wq1[a * 9 + 3 + dx];
          const float wb = wq1[a * 9 + 6 + dx];
          q0 = pkfma(wt, T.p[dx], q0);
          q1 = pkfma(wt, T.p[dx + 2], q1);
          q0 = pkfma(wm, M.p[dx], q0);
          q1 = pkfma(wm, M.p[dx + 2], q1);
          q0 = pkfma(wb, B.p[dx], q0);
          q1 = pkfma(wb, B.p[dx + 2], q1);
        }
        m0 = a ? pkmax(m0, q0) : q0;
        m1 = a ? pkmax(m1, q1) : q1;
      }
      vreg[0] = m0; vreg[1] = m1;
      *(float4*)&dst[row + 1][colb + 4] = make_float4(m0.x, m0.y, m1.x, m1.y);
      __syncthreads();
    }
  }
  // v19 in v_s[0]

  // ---- stage 4: q20 at query points + softmax over ACT ----
  // NOTE: a = tid&7 is NOT wave-uniform -> plain per-lane loads here (no uload,
  // no dynamic indexing into the wq1 register array).
  if (tid < 64 * ACT) {
    const int k = tid >> 3;
    const int a = tid & 7;
    const int qy = s12_s[k];
    const int qx = s12_s[64 + k];
    float accq = 0.f;
    #pragma unroll
    for (int dy = 0; dy < 3; ++dy)
      #pragma unroll
      for (int dx = 0; dx < 3; ++dx) {
        const float w0 = Wq[a * 18 + dy * 3 + dx];
        const float w1 = Wq[a * 18 + 9 + dy * 3 + dx];
        accq += w0 * r_s[qy + dy][qx + dx + 3];
        accq += w1 * v_s[0][qy + dy][qx + dx + 3];
      }
    float m = accq;
    m = fmaxf(m, __shfl_xor(m, 1));
    m = fmaxf(m, __shfl_xor(m, 2));
    m = fmaxf(m, __shfl_xor(m, 4));
    const float e = __expf(accq - m);
    float s = e;
    s += __shfl_xor(s, 1);
    s += __shfl_xor(s, 2);
    s += __shfl_xor(s, 4);
    out[tid] = e / s;
  }
}

extern "C" void kernel_launch(void* const* d_in, const int* in_sizes, int n_in,
                              void* d_out, int out_size, void* d_ws, size_t ws_size,
                              hipStream_t stream) {
  const float* X  = (const float*)d_in[0];
  const int*   S1 = (const int*)d_in[1];
  const int*   S2 = (const int*)d_in[2];
  const float* Wh = (const float*)d_in[3];
  const float* bh = (const float*)d_in[4];
  const float* Wr = (const float*)d_in[5];
  const float* Wq = (const float*)d_in[6];
  float* out = (float*)d_out;

  vin_kernel<<<1, 1024, 0, stream>>>(X, S1, S2, Wh, bh, Wr, Wq, out);
}

// Round 6
// 114.436 us; speedup vs baseline: 1.3931x; 1.0481x over previous
//
#include <hip/hip_runtime.h>

// VIN on one CU, 1024 threads. R6: 2x2 cells/thread; horizontal cell pair is a
// native v2f (pk-friendly); horizontal neighbors via DPP wave_shr/shl (VALU
// pipe, zero DS, bound_ctrl gives the zero halo); vertical via registers +
// tiny conflict-free b64 boundary exchange in LDS (ping-pong). This collapses
// the per-step DS-pipe convoy (~1.1 us/step) and the window-rebuild movs.

#define ACT 8
#define HID 150
#define STR 76

typedef float v2f __attribute__((ext_vector_type(2)));

__device__ __forceinline__ v2f pkfma(float w, v2f b, v2f c) {
  return __builtin_elementwise_fma((v2f){w, w}, b, c);
}
__device__ __forceinline__ v2f pkmax(v2f a, v2f b) {
  return __builtin_elementwise_max(a, b);
}
// Wave-uniform load -> SGPR. PRECONDITION: address identical across the wave.
__device__ __forceinline__ float uload(const float* p) {
  return __int_as_float(__builtin_amdgcn_readfirstlane(__float_as_int(*p)));
}
// lane l <- l-1 (wave_shr:1), lane 0 -> 0. old=0 so invalid lanes are 0 under
// either bound_ctrl interpretation.
__device__ __forceinline__ float lane_prev(float x) {
  return __int_as_float(
      __builtin_amdgcn_update_dpp(0, __float_as_int(x), 0x138, 0xF, 0xF, true));
}
// lane l <- l+1 (wave_shl:1), lane 63 -> 0.
__device__ __forceinline__ float lane_next(float x) {
  return __int_as_float(
      __builtin_amdgcn_update_dpp(0, __float_as_int(x), 0x130, 0xF, 0xF, true));
}

__launch_bounds__(1024, 4)
__global__ void vin_kernel(const float* __restrict__ X,
                           const int*   __restrict__ S1,
                           const int*   __restrict__ S2,
                           const float* __restrict__ Wh,
                           const float* __restrict__ bh,
                           const float* __restrict__ Wr,
                           const float* __restrict__ Wq,
                           float*       __restrict__ out) {
  __shared__ float r_s[66][STR];       // r map + zero halo (stage 2 & 4)
  __shared__ float v_s[66][STR];       // v19 + zero halo (stage 4 only)
  __shared__ v2f   tb[2][34][32];      // ping-pong: top row (2ty) of each band
  __shared__ v2f   bb[2][34][32];      // ping-pong: bottom row (2ty+1)
  __shared__ float weff_s[19];
  __shared__ int   s12_s[128];

  const int tid  = threadIdx.x;
  const int tx   = tid & 31;           // col pair index: cols 2tx, 2tx+1
  const int ty   = tid >> 5;           // row pair index: rows 2ty, 2ty+1
  const int lane = tid & 63;
  // mid-wave band crossing fixups (lanes 0/63 are zeroed by DPP bound_ctrl)
  const float zp = (lane == 32) ? 0.f : 1.f;
  const float zn = (lane == 31) ? 0.f : 1.f;
  const int R  = ty << 1;
  const int cc = tx << 1;

  { // ---- zero LDS (halo rows/cols must stay 0; tb/bb rows 0 and 33 = halo) ----
    const float4 z = make_float4(0.f, 0.f, 0.f, 0.f);
    float4* a = (float4*)&r_s[0][0];
    for (int i = tid; i < 66 * STR / 4; i += 1024) a[i] = z;
    float4* b = (float4*)&v_s[0][0];
    for (int i = tid; i < 66 * STR / 4; i += 1024) b[i] = z;
    float4* c = (float4*)&tb[0][0][0];
    for (int i = tid; i < 2 * 34 * 32 / 2; i += 1024) c[i] = z;
    float4* d = (float4*)&bb[0][0][0];
    for (int i = tid; i < 2 * 34 * 32 / 2; i += 1024) d[i] = z;
  }
  if (tid < 128) s12_s[tid] = (tid < 64) ? S1[tid] : S2[tid - 64];

  // ---- weff contraction: 19 outputs x 32 lanes, parallel + shfl reduce ----
  if (tid < 19 * 32) {
    const int t = tid >> 5, ln = tid & 31;
    float acc = 0.f;
    #pragma unroll
    for (int i = 0; i < 5; ++i) {
      const int h = ln + 32 * i;
      if (h < HID) acc += Wr[h] * (t < 18 ? Wh[h * 18 + t] : bh[h]);
    }
    acc += __shfl_xor(acc, 1);
    acc += __shfl_xor(acc, 2);
    acc += __shfl_xor(acc, 4);
    acc += __shfl_xor(acc, 8);
    acc += __shfl_xor(acc, 16);
    if (ln == 0) weff_s[t] = acc;
  }
  __syncthreads();

  // ---- stage 1: r = conv3x3(X, Weff) + beff, straight from global X ----
  v2f ra, rb;   // own r rows 2ty, 2ty+1 (col pair)
  {
    v2f xx[2][4];
    #pragma unroll
    for (int ch = 0; ch < 2; ++ch)
      #pragma unroll
      for (int dy = 0; dy < 4; ++dy) {
        const int row = R - 1 + dy;
        xx[ch][dy] = (row >= 0 && row < 64)
                   ? *(const v2f*)&X[ch * 4096 + row * 64 + cc]
                   : (v2f){0.f, 0.f};
      }
    float wl[18];
    #pragma unroll
    for (int t = 0; t < 18; ++t) wl[t] = weff_s[t];
    const float beff = weff_s[18];
    v2f a0 = (v2f){beff, beff}, a1 = a0;
    #pragma unroll
    for (int ch = 0; ch < 2; ++ch) {
      v2f L[4], Rr[4];
      #pragma unroll
      for (int i = 0; i < 4; ++i) {
        L[i]  = (v2f){lane_prev(xx[ch][i].y) * zp, xx[ch][i].x};
        Rr[i] = (v2f){xx[ch][i].y, lane_next(xx[ch][i].x) * zn};
      }
      #pragma unroll
      for (int dy = 0; dy < 3; ++dy) {
        const float w0 = wl[ch * 9 + dy * 3 + 0];
        const float w1 = wl[ch * 9 + dy * 3 + 1];
        const float w2 = wl[ch * 9 + dy * 3 + 2];
        a0 = pkfma(w0, L[dy], a0);     a0 = pkfma(w1, xx[ch][dy], a0);
        a0 = pkfma(w2, Rr[dy], a0);
        a1 = pkfma(w0, L[dy + 1], a1); a1 = pkfma(w1, xx[ch][dy + 1], a1);
        a1 = pkfma(w2, Rr[dy + 1], a1);
      }
    }
    *(v2f*)&r_s[R + 1][cc + 4] = a0;
    *(v2f*)&r_s[R + 2][cc + 4] = a1;
    ra = a0; rb = a1;
  }
  __syncthreads();

  // ---- stage 2: qr = conv3x3(r, Wq[:,0]) (iteration-invariant); v1 = max ----
  v2f qr0[ACT], qr1[ACT], v0, v1;
  {
    v2f rows[4];
    rows[0] = *(const v2f*)&r_s[R][cc + 4];       // r row 2ty-1 (halo-safe)
    rows[1] = ra;
    rows[2] = rb;
    rows[3] = *(const v2f*)&r_s[R + 3][cc + 4];   // r row 2ty+2
    v2f L[4], Rr[4];
    #pragma unroll
    for (int i = 0; i < 4; ++i) {
      L[i]  = (v2f){lane_prev(rows[i].y) * zp, rows[i].x};
      Rr[i] = (v2f){rows[i].y, lane_next(rows[i].x) * zn};
    }
    #pragma unroll
    for (int a = 0; a < ACT; ++a) {
      v2f q0 = (v2f){0.f, 0.f}, q1 = (v2f){0.f, 0.f};
      #pragma unroll
      for (int dy = 0; dy < 3; ++dy) {
        const float w0 = uload(&Wq[a * 18 + dy * 3 + 0]);  // uniform index
        const float w1 = uload(&Wq[a * 18 + dy * 3 + 1]);
        const float w2 = uload(&Wq[a * 18 + dy * 3 + 2]);
        q0 = pkfma(w0, L[dy], q0);     q0 = pkfma(w1, rows[dy], q0);
        q0 = pkfma(w2, Rr[dy], q0);
        q1 = pkfma(w0, L[dy + 1], q1); q1 = pkfma(w1, rows[dy + 1], q1);
        q1 = pkfma(w2, Rr[dy + 1], q1);
      }
      qr0[a] = q0; qr1[a] = q1;
      v0 = a ? pkmax(v0, q0) : q0;
      v1 = a ? pkmax(v1, q1) : q1;
    }
    tb[0][ty + 1][tx] = v0;
    bb[0][ty + 1][tx] = v1;
  }

  // ---- pin all VI-loop weights wave-uniform (indices are unroll constants) ----
  float wq1[72];
  #pragma unroll
  for (int a = 0; a < ACT; ++a)
    #pragma unroll
    for (int t = 0; t < 9; ++t) wq1[a * 9 + t] = uload(&Wq[a * 18 + 9 + t]);
  __syncthreads();

  // ---- stage 3: 18 VI updates; per step: 2 b64 reads, 12 DPP, 144 pkfma,
  //      2 b64 writes, 1 barrier ----
  #pragma unroll 1
  for (int it = 0; it < 9; ++it) {
    #pragma unroll
    for (int p = 0; p < 2; ++p) {
      v2f rows[4];
      rows[0] = bb[p][ty][tx];        // v row 2ty-1 (halo row 0 = zeros)
      rows[1] = v0;
      rows[2] = v1;
      rows[3] = tb[p][ty + 2][tx];    // v row 2ty+2 (halo row 33 = zeros)
      v2f L[4], Rr[4];
      #pragma unroll
      for (int i = 0; i < 4; ++i) {
        L[i]  = (v2f){lane_prev(rows[i].y) * zp, rows[i].x};
        Rr[i] = (v2f){rows[i].y, lane_next(rows[i].x) * zn};
      }
      v2f m0, m1;
      #pragma unroll
      for (int a = 0; a < ACT; ++a) {
        v2f q0 = qr0[a], q1 = qr1[a];
        #pragma unroll
        for (int dy = 0; dy < 3; ++dy) {
          const float w0 = wq1[a * 9 + dy * 3 + 0];
          const float w1 = wq1[a * 9 + dy * 3 + 1];
          const float w2 = wq1[a * 9 + dy * 3 + 2];
          q0 = pkfma(w0, L[dy], q0);     q0 = pkfma(w1, rows[dy], q0);
          q0 = pkfma(w2, Rr[dy], q0);
          q1 = pkfma(w0, L[dy + 1], q1); q1 = pkfma(w1, rows[dy + 1], q1);
          q1 = pkfma(w2, Rr[dy + 1], q1);
        }
        m0 = a ? pkmax(m0, q0) : q0;
        m1 = a ? pkmax(m1, q1) : q1;
      }
      v0 = m0; v1 = m1;
      tb[p ^ 1][ty + 1][tx] = v0;
      bb[p ^ 1][ty + 1][tx] = v1;
      __syncthreads();
    }
  }
  // v19 in (v0, v1) registers

  *(v2f*)&v_s[R + 1][cc + 4] = v0;
  *(v2f*)&v_s[R + 2][cc + 4] = v1;
  __syncthreads();

  // ---- stage 4: q20 at query points + softmax over ACT (per-lane Wq loads:
  //      a = tid&7 is NOT wave-uniform) ----
  if (tid < 64 * ACT) {
    const int k = tid >> 3;
    const int a = tid & 7;
    const int qy = s12_s[k];
    const int qx = s12_s[64 + k];
    float accq = 0.f;
    #pragma unroll
    for (int dy = 0; dy < 3; ++dy)
      #pragma unroll
      for (int dx = 0; dx < 3; ++dx) {
        const float w0 = Wq[a * 18 + dy * 3 + dx];
        const float w1 = Wq[a * 18 + 9 + dy * 3 + dx];
        accq += w0 * r_s[qy + dy][qx + dx + 3];
        accq += w1 * v_s[qy + dy][qx + dx + 3];
      }
    float m = accq;
    m = fmaxf(m, __shfl_xor(m, 1));
    m = fmaxf(m, __shfl_xor(m, 2));
    m = fmaxf(m, __shfl_xor(m, 4));
    const float e = __expf(accq - m);
    float s = e;
    s += __shfl_xor(s, 1);
    s += __shfl_xor(s, 2);
    s += __shfl_xor(s, 4);
    out[tid] = e / s;
  }
}

extern "C" void kernel_launch(void* const* d_in, const int* in_sizes, int n_in,
                              void* d_out, int out_size, void* d_ws, size_t ws_size,
                              hipStream_t stream) {
  const float* X  = (const float*)d_in[0];
  const int*   S1 = (const int*)d_in[1];
  const int*   S2 = (const int*)d_in[2];
  const float* Wh = (const float*)d_in[3];
  const float* bh = (const float*)d_in[4];
  const float* Wr = (const float*)d_in[5];
  const float* Wq = (const float*)d_in[6];
  float* out = (float*)d_out;

  vin_kernel<<<1, 1024, 0, stream>>>(X, S1, S2, Wh, bh, Wr, Wq, out);
}

// Round 9
// 96.884 us; speedup vs baseline: 1.6455x; 1.1812x over previous
//
#include <hip/hip_runtime.h>

// VIN on one CU, 1024 threads. R9 = R8 with v_pk_max_f32 removed:
// gfx950 has NO packed fp32 max (CDNA packed-f32 set: pk_fma/pk_mul/pk_add/
// pk_mov only). Max is scalar v_max_f32 (compiler may fuse to v_max3_f32).
// v_pk_fma_f32 with SGPR-pair scalar src0 + op_sel dword select assembled
// cleanly in R8 -> kept: 2 FMA/instr, zero VGPR weight cost.
// Layout (R6, verified exact): 2x2 cells/thread, horizontal neighbors via DPP
// wave_shr/shl (bound_ctrl zero = grid halo), vertical via registers + b64
// conflict-free band-boundary exchange in LDS (ping-pong), 1 barrier/step.

#define ACT 8
#define HID 150
#define STR 76

typedef float v2f __attribute__((ext_vector_type(2)));
typedef unsigned long long u64;

// packed FMA, weight = selected dword of SGPR pair broadcast to both halves
__device__ __forceinline__ void pkfma_lo(v2f& acc, u64 wp, v2f x) {
  asm("v_pk_fma_f32 %0, %1, %2, %0 op_sel:[0,0,0] op_sel_hi:[0,1,1]"
      : "+v"(acc) : "s"(wp), "v"(x));
}
__device__ __forceinline__ void pkfma_hi(v2f& acc, u64 wp, v2f x) {
  asm("v_pk_fma_f32 %0, %1, %2, %0 op_sel:[1,0,0] op_sel_hi:[1,1,1]"
      : "+v"(acc) : "s"(wp), "v"(x));
}
__device__ __forceinline__ void pkfma_s(v2f& acc, u64 wp, int half, v2f x) {
  if (half == 0) pkfma_lo(acc, wp, x); else pkfma_hi(acc, wp, x);
}
// no v_pk_max_f32 on gfx950 -> scalar (compiler can fuse into v_max3_f32)
__device__ __forceinline__ v2f cmax(v2f a, v2f b) {
  return (v2f){fmaxf(a.x, b.x), fmaxf(a.y, b.y)};
}
// scalarized v2f fma for one-shot stages
__device__ __forceinline__ v2f cfma(float w, v2f x, v2f acc) {
  acc.x = fmaf(w, x.x, acc.x);
  acc.y = fmaf(w, x.y, acc.y);
  return acc;
}
// Wave-uniform load -> SGPR. PRECONDITION: address identical across the wave.
__device__ __forceinline__ float uload(const float* p) {
  return __int_as_float(__builtin_amdgcn_readfirstlane(__float_as_int(*p)));
}
// lane l <- l-1 (wave_shr:1), lane 0 -> 0.
__device__ __forceinline__ float lane_prev(float x) {
  return __int_as_float(
      __builtin_amdgcn_update_dpp(0, __float_as_int(x), 0x138, 0xF, 0xF, true));
}
// lane l <- l+1 (wave_shl:1), lane 63 -> 0.
__device__ __forceinline__ float lane_next(float x) {
  return __int_as_float(
      __builtin_amdgcn_update_dpp(0, __float_as_int(x), 0x130, 0xF, 0xF, true));
}

__launch_bounds__(1024, 4)
__global__ void vin_kernel(const float* __restrict__ X,
                           const int*   __restrict__ S1,
                           const int*   __restrict__ S2,
                           const float* __restrict__ Wh,
                           const float* __restrict__ bh,
                           const float* __restrict__ Wr,
                           const float* __restrict__ Wq,
                           float*       __restrict__ out) {
  __shared__ float r_s[66][STR];       // r map + zero halo (stage 2 & 4)
  __shared__ float v_s[66][STR];       // v19 + zero halo (stage 4 only)
  __shared__ v2f   tb[2][34][32];      // ping-pong: top row (2ty) of each band
  __shared__ v2f   bb[2][34][32];      // ping-pong: bottom row (2ty+1)
  __shared__ float weff_s[19];
  __shared__ int   s12_s[128];

  const int tid  = threadIdx.x;
  const int tx   = tid & 31;           // col pair index: cols 2tx, 2tx+1
  const int ty   = tid >> 5;           // row pair index: rows 2ty, 2ty+1
  const int lane = tid & 63;
  // mid-wave band crossing fixups (lanes 0/63 are zeroed by DPP bound_ctrl)
  const float zp = (lane == 32) ? 0.f : 1.f;
  const float zn = (lane == 31) ? 0.f : 1.f;
  const int R  = ty << 1;
  const int cc = tx << 1;

  { // ---- zero LDS (halo rows/cols must stay 0; tb/bb rows 0 and 33 = halo) ----
    const float4 z = make_float4(0.f, 0.f, 0.f, 0.f);
    float4* a = (float4*)&r_s[0][0];
    for (int i = tid; i < 66 * STR / 4; i += 1024) a[i] = z;
    float4* b = (float4*)&v_s[0][0];
    for (int i = tid; i < 66 * STR / 4; i += 1024) b[i] = z;
    float4* c = (float4*)&tb[0][0][0];
    for (int i = tid; i < 2 * 34 * 32 / 2; i += 1024) c[i] = z;
    float4* d = (float4*)&bb[0][0][0];
    for (int i = tid; i < 2 * 34 * 32 / 2; i += 1024) d[i] = z;
  }
  if (tid < 128) s12_s[tid] = (tid < 64) ? S1[tid] : S2[tid - 64];

  // ---- weff contraction: 19 outputs x 32 lanes, parallel + shfl reduce ----
  if (tid < 19 * 32) {
    const int t = tid >> 5, ln = tid & 31;
    float acc = 0.f;
    #pragma unroll
    for (int i = 0; i < 5; ++i) {
      const int h = ln + 32 * i;
      if (h < HID) acc += Wr[h] * (t < 18 ? Wh[h * 18 + t] : bh[h]);
    }
    acc += __shfl_xor(acc, 1);
    acc += __shfl_xor(acc, 2);
    acc += __shfl_xor(acc, 4);
    acc += __shfl_xor(acc, 8);
    acc += __shfl_xor(acc, 16);
    if (ln == 0) weff_s[t] = acc;
  }
  __syncthreads();

  // ---- stage 1: r = conv3x3(X, Weff) + beff, straight from global X ----
  v2f ra, rb;   // own r rows 2ty, 2ty+1 (col pair)
  {
    v2f xx[2][4];
    #pragma unroll
    for (int ch = 0; ch < 2; ++ch)
      #pragma unroll
      for (int dy = 0; dy < 4; ++dy) {
        const int row = R - 1 + dy;
        xx[ch][dy] = (row >= 0 && row < 64)
                   ? *(const v2f*)&X[ch * 4096 + row * 64 + cc]
                   : (v2f){0.f, 0.f};
      }
    float wl[18];
    #pragma unroll
    for (int t = 0; t < 18; ++t) wl[t] = uload(&weff_s[t]);
    const float beff = uload(&weff_s[18]);
    v2f a0 = (v2f){beff, beff}, a1 = a0;
    #pragma unroll
    for (int ch = 0; ch < 2; ++ch) {
      v2f L[4], Rr[4];
      #pragma unroll
      for (int i = 0; i < 4; ++i) {
        L[i]  = (v2f){lane_prev(xx[ch][i].y) * zp, xx[ch][i].x};
        Rr[i] = (v2f){xx[ch][i].y, lane_next(xx[ch][i].x) * zn};
      }
      #pragma unroll
      for (int dy = 0; dy < 3; ++dy) {
        const float w0 = wl[ch * 9 + dy * 3 + 0];
        const float w1 = wl[ch * 9 + dy * 3 + 1];
        const float w2 = wl[ch * 9 + dy * 3 + 2];
        a0 = cfma(w0, L[dy], a0);     a0 = cfma(w1, xx[ch][dy], a0);
        a0 = cfma(w2, Rr[dy], a0);
        a1 = cfma(w0, L[dy + 1], a1); a1 = cfma(w1, xx[ch][dy + 1], a1);
        a1 = cfma(w2, Rr[dy + 1], a1);
      }
    }
    *(v2f*)&r_s[R + 1][cc + 4] = a0;
    *(v2f*)&r_s[R + 2][cc + 4] = a1;
    ra = a0; rb = a1;
  }
  __syncthreads();

  // ---- stage 2: qr = conv3x3(r, Wq[:,0]) (iteration-invariant); v1 = max ----
  v2f qr0[ACT], qr1[ACT], v0, v1;
  {
    v2f rows[4];
    rows[0] = *(const v2f*)&r_s[R][cc + 4];       // r row 2ty-1 (halo-safe)
    rows[1] = ra;
    rows[2] = rb;
    rows[3] = *(const v2f*)&r_s[R + 3][cc + 4];   // r row 2ty+2
    v2f L[4], Rr[4];
    #pragma unroll
    for (int i = 0; i < 4; ++i) {
      L[i]  = (v2f){lane_prev(rows[i].y) * zp, rows[i].x};
      Rr[i] = (v2f){rows[i].y, lane_next(rows[i].x) * zn};
    }
    #pragma unroll
    for (int a = 0; a < ACT; ++a) {
      v2f q0 = (v2f){0.f, 0.f}, q1 = (v2f){0.f, 0.f};
      #pragma unroll
      for (int dy = 0; dy < 3; ++dy) {
        const float w0 = uload(&Wq[a * 18 + dy * 3 + 0]);  // uniform index
        const float w1 = uload(&Wq[a * 18 + dy * 3 + 1]);
        const float w2 = uload(&Wq[a * 18 + dy * 3 + 2]);
        q0 = cfma(w0, L[dy], q0);     q0 = cfma(w1, rows[dy], q0);
        q0 = cfma(w2, Rr[dy], q0);
        q1 = cfma(w0, L[dy + 1], q1); q1 = cfma(w1, rows[dy + 1], q1);
        q1 = cfma(w2, Rr[dy + 1], q1);
      }
      qr0[a] = q0; qr1[a] = q1;
      v0 = a ? cmax(v0, q0) : q0;
      v1 = a ? cmax(v1, q1) : q1;
    }
    tb[0][ty + 1][tx] = v0;
    bb[0][ty + 1][tx] = v1;
  }

  // ---- pin VI-loop weights: 2 consecutive weights per SGPR pair (36 pairs) ----
  u64 wqp[36];
  #pragma unroll
  for (int p = 0; p < 36; ++p) {
    const int w0 = 2 * p, w1 = 2 * p + 1;   // weight idx = a*9 + t
    const unsigned lo = (unsigned)__builtin_amdgcn_readfirstlane(
        __float_as_int(Wq[(w0 / 9) * 18 + 9 + (w0 % 9)]));
    const unsigned hi = (unsigned)__builtin_amdgcn_readfirstlane(
        __float_as_int(Wq[(w1 / 9) * 18 + 9 + (w1 % 9)]));
    wqp[p] = (u64)lo | ((u64)hi << 32);
  }
  __syncthreads();

  // ---- stage 3: 18 VI updates; per step: 2 b64 reads, 8 DPP, 144 v_pk_fma,
  //      ~28 v_max (fusable to max3), 2 b64 writes, 1 barrier ----
  #pragma unroll 1
  for (int it = 0; it < 9; ++it) {
    #pragma unroll
    for (int p = 0; p < 2; ++p) {
      v2f rows[4];
      rows[0] = bb[p][ty][tx];        // v row 2ty-1 (halo row 0 = zeros)
      rows[1] = v0;
      rows[2] = v1;
      rows[3] = tb[p][ty + 2][tx];    // v row 2ty+2 (halo row 33 = zeros)
      v2f L[4], Rr[4];
      #pragma unroll
      for (int i = 0; i < 4; ++i) {
        L[i]  = (v2f){lane_prev(rows[i].y) * zp, rows[i].x};
        Rr[i] = (v2f){rows[i].y, lane_next(rows[i].x) * zn};
      }
      v2f m0, m1;
      #pragma unroll
      for (int a = 0; a < ACT; ++a) {
        v2f q0 = qr0[a], q1 = qr1[a];
        #pragma unroll
        for (int dy = 0; dy < 3; ++dy) {
          const int w0 = a * 9 + dy * 3 + 0;
          const int w1 = a * 9 + dy * 3 + 1;
          const int w2 = a * 9 + dy * 3 + 2;
          pkfma_s(q0, wqp[w0 >> 1], w0 & 1, L[dy]);
          pkfma_s(q0, wqp[w1 >> 1], w1 & 1, rows[dy]);
          pkfma_s(q0, wqp[w2 >> 1], w2 & 1, Rr[dy]);
          pkfma_s(q1, wqp[w0 >> 1], w0 & 1, L[dy + 1]);
          pkfma_s(q1, wqp[w1 >> 1], w1 & 1, rows[dy + 1]);
          pkfma_s(q1, wqp[w2 >> 1], w2 & 1, Rr[dy + 1]);
        }
        m0 = a ? cmax(m0, q0) : q0;
        m1 = a ? cmax(m1, q1) : q1;
      }
      v0 = m0; v1 = m1;
      tb[p ^ 1][ty + 1][tx] = v0;
      bb[p ^ 1][ty + 1][tx] = v1;
      __syncthreads();
    }
  }
  // v19 in (v0, v1) registers

  *(v2f*)&v_s[R + 1][cc + 4] = v0;
  *(v2f*)&v_s[R + 2][cc + 4] = v1;
  __syncthreads();

  // ---- stage 4: q20 at query points + softmax over ACT (per-lane Wq loads:
  //      a = tid&7 is NOT wave-uniform) ----
  if (tid < 64 * ACT) {
    const int k = tid >> 3;
    const int a = tid & 7;
    const int qy = s12_s[k];
    const int qx = s12_s[64 + k];
    float accq = 0.f;
    #pragma unroll
    for (int dy = 0; dy < 3; ++dy)
      #pragma unroll
      for (int dx = 0; dx < 3; ++dx) {
        const float w0 = Wq[a * 18 + dy * 3 + dx];
        const float w1 = Wq[a * 18 + 9 + dy * 3 + dx];
        accq += w0 * r_s[qy + dy][qx + dx + 3];
        accq += w1 * v_s[qy + dy][qx + dx + 3];
      }
    float m = accq;
    m = fmaxf(m, __shfl_xor(m, 1));
    m = fmaxf(m, __shfl_xor(m, 2));
    m = fmaxf(m, __shfl_xor(m, 4));
    const float e = __expf(accq - m);
    float s = e;
    s += __shfl_xor(s, 1);
    s += __shfl_xor(s, 2);
    s += __shfl_xor(s, 4);
    out[tid] = e / s;
  }
}

extern "C" void kernel_launch(void* const* d_in, const int* in_sizes, int n_in,
                              void* d_out, int out_size, void* d_ws, size_t ws_size,
                              hipStream_t stream) {
  const float* X  = (const float*)d_in[0];
  const int*   S1 = (const int*)d_in[1];
  const int*   S2 = (const int*)d_in[2];
  const float* Wh = (const float*)d_in[3];
  const float* bh = (const float*)d_in[4];
  const float* Wr = (const float*)d_in[5];
  const float* Wq = (const float*)d_in[6];
  float* out = (float*)d_out;

  vin_kernel<<<1, 1024, 0, stream>>>(X, S1, S2, Wh, bh, Wr, Wq, out);
}

// Round 10
// 91.577 us; speedup vs baseline: 1.7408x; 1.0579x over previous
//
#include <hip/hip_runtime.h>

// VIN, R10: 2-workgroup redundant-halo trapezoid (row split), R9 core intact.
// No inter-WG sync: each WG computes a shrinking row-trapezoid (halo 18 = VI
// depth). WG0: local rows = global 0..51, final valid rows 0..32 (queries
// qy<=31). WG1: base row 12, local 0..51 = global 12..63, valid >= 31
// (queries qy>=32). r is EXACT everywhere (from global X); contaminated
// v-rows provably stay outside the shrinking valid region (incl. stale
// boundary bands). Per-step active predicate: WG0 Rl<=49-s, WG1 Rl>=s+1.
// Core per step (verified R9): 144 v_pk_fma_f32 (SGPR-pair weights via
// op_sel), DPP horizontal neighbors, b64 band-boundary LDS, 1 barrier.

#define ACT 8
#define HID 150
#define STR 76
#define NB   26          // row-pair bands per WG
#define NTHR (NB * 32)   // 832 threads = 13 waves

typedef float v2f __attribute__((ext_vector_type(2)));
typedef unsigned long long u64;

__device__ __forceinline__ void pkfma_lo(v2f& acc, u64 wp, v2f x) {
  asm("v_pk_fma_f32 %0, %1, %2, %0 op_sel:[0,0,0] op_sel_hi:[0,1,1]"
      : "+v"(acc) : "s"(wp), "v"(x));
}
__device__ __forceinline__ void pkfma_hi(v2f& acc, u64 wp, v2f x) {
  asm("v_pk_fma_f32 %0, %1, %2, %0 op_sel:[1,0,0] op_sel_hi:[1,1,1]"
      : "+v"(acc) : "s"(wp), "v"(x));
}
__device__ __forceinline__ void pkfma_s(v2f& acc, u64 wp, int half, v2f x) {
  if (half == 0) pkfma_lo(acc, wp, x); else pkfma_hi(acc, wp, x);
}
__device__ __forceinline__ v2f cmax(v2f a, v2f b) {
  return (v2f){fmaxf(a.x, b.x), fmaxf(a.y, b.y)};
}
__device__ __forceinline__ v2f cfma(float w, v2f x, v2f acc) {
  acc.x = fmaf(w, x.x, acc.x);
  acc.y = fmaf(w, x.y, acc.y);
  return acc;
}
__device__ __forceinline__ float uload(const float* p) {  // wave-uniform only
  return __int_as_float(__builtin_amdgcn_readfirstlane(__float_as_int(*p)));
}
__device__ __forceinline__ float lane_prev(float x) {  // wave_shr:1, lane0->0
  return __int_as_float(
      __builtin_amdgcn_update_dpp(0, __float_as_int(x), 0x138, 0xF, 0xF, true));
}
__device__ __forceinline__ float lane_next(float x) {  // wave_shl:1, lane63->0
  return __int_as_float(
      __builtin_amdgcn_update_dpp(0, __float_as_int(x), 0x130, 0xF, 0xF, true));
}

__launch_bounds__(NTHR, 4)
__global__ void vin_kernel(const float* __restrict__ X,
                           const int*   __restrict__ S1,
                           const int*   __restrict__ S2,
                           const float* __restrict__ Wh,
                           const float* __restrict__ bh,
                           const float* __restrict__ Wr,
                           const float* __restrict__ Wq,
                           float*       __restrict__ out) {
  __shared__ float r_s[54][STR];       // local rows -1..52 (index = local+1)
  __shared__ float v_s[54][STR];       // v19, same indexing
  __shared__ v2f   tb[2][28][32];      // ping-pong: band top rows (+halo 0,27)
  __shared__ v2f   bb[2][28][32];      // ping-pong: band bottom rows
  __shared__ float weff_s[19];
  __shared__ int   s12_s[128];

  const int tid  = threadIdx.x;
  const int tx   = tid & 31;
  const int ty   = tid >> 5;           // 0..25
  const int lane = tid & 63;
  const float zp = (lane == 32) ? 0.f : 1.f;   // mid-wave band-crossing fixups
  const float zn = (lane == 31) ? 0.f : 1.f;
  const int Rl = ty << 1;              // local row of band top
  const int cc = tx << 1;
  const int wg = blockIdx.x;           // 0 or 1
  const int B  = wg * 12;              // global row base (WG1: rows 12..63)

  { // zero LDS (halos must be 0)
    const float4 z = make_float4(0.f, 0.f, 0.f, 0.f);
    float4* a = (float4*)&r_s[0][0];
    for (int i = tid; i < 54 * STR / 4; i += NTHR) a[i] = z;
    float4* b = (float4*)&v_s[0][0];
    for (int i = tid; i < 54 * STR / 4; i += NTHR) b[i] = z;
    float4* c = (float4*)&tb[0][0][0];
    for (int i = tid; i < 2 * 28 * 32 / 2; i += NTHR) c[i] = z;
    float4* d = (float4*)&bb[0][0][0];
    for (int i = tid; i < 2 * 28 * 32 / 2; i += NTHR) d[i] = z;
  }
  if (tid < 128) s12_s[tid] = (tid < 64) ? S1[tid] : S2[tid - 64];

  // weff contraction: 19 outputs x 32 lanes
  if (tid < 19 * 32) {
    const int t = tid >> 5, ln = tid & 31;
    float acc = 0.f;
    #pragma unroll
    for (int i = 0; i < 5; ++i) {
      const int h = ln + 32 * i;
      if (h < HID) acc += Wr[h] * (t < 18 ? Wh[h * 18 + t] : bh[h]);
    }
    acc += __shfl_xor(acc, 1);
    acc += __shfl_xor(acc, 2);
    acc += __shfl_xor(acc, 4);
    acc += __shfl_xor(acc, 8);
    acc += __shfl_xor(acc, 16);
    if (ln == 0) weff_s[t] = acc;
  }
  __syncthreads();

  // ---- stage 1: r EXACT on local rows 0..51 (X read at global rows) ----
  v2f ra, rb;
  {
    v2f xx[2][4];
    #pragma unroll
    for (int ch = 0; ch < 2; ++ch)
      #pragma unroll
      for (int dy = 0; dy < 4; ++dy) {
        const int g = B + Rl - 1 + dy;    // global row
        xx[ch][dy] = (g >= 0 && g < 64)
                   ? *(const v2f*)&X[ch * 4096 + g * 64 + cc]
                   : (v2f){0.f, 0.f};
      }
    float wl[18];
    #pragma unroll
    for (int t = 0; t < 18; ++t) wl[t] = uload(&weff_s[t]);
    const float beff = uload(&weff_s[18]);
    v2f a0 = (v2f){beff, beff}, a1 = a0;
    #pragma unroll
    for (int ch = 0; ch < 2; ++ch) {
      v2f L[4], Rr[4];
      #pragma unroll
      for (int i = 0; i < 4; ++i) {
        L[i]  = (v2f){lane_prev(xx[ch][i].y) * zp, xx[ch][i].x};
        Rr[i] = (v2f){xx[ch][i].y, lane_next(xx[ch][i].x) * zn};
      }
      #pragma unroll
      for (int dy = 0; dy < 3; ++dy) {
        const float w0 = wl[ch * 9 + dy * 3 + 0];
        const float w1 = wl[ch * 9 + dy * 3 + 1];
        const float w2 = wl[ch * 9 + dy * 3 + 2];
        a0 = cfma(w0, L[dy], a0);     a0 = cfma(w1, xx[ch][dy], a0);
        a0 = cfma(w2, Rr[dy], a0);
        a1 = cfma(w0, L[dy + 1], a1); a1 = cfma(w1, xx[ch][dy + 1], a1);
        a1 = cfma(w2, Rr[dy + 1], a1);
      }
    }
    *(v2f*)&r_s[Rl + 1][cc + 4] = a0;
    *(v2f*)&r_s[Rl + 2][cc + 4] = a1;
    ra = a0; rb = a1;
  }
  __syncthreads();

  // ---- stage 2: qr (iteration-invariant); v1 = max_a qr ----
  v2f qr0[ACT], qr1[ACT], v0, v1;
  {
    v2f rows[4];
    rows[0] = *(const v2f*)&r_s[Rl][cc + 4];
    rows[1] = ra;
    rows[2] = rb;
    rows[3] = *(const v2f*)&r_s[Rl + 3][cc + 4];
    v2f L[4], Rr[4];
    #pragma unroll
    for (int i = 0; i < 4; ++i) {
      L[i]  = (v2f){lane_prev(rows[i].y) * zp, rows[i].x};
      Rr[i] = (v2f){rows[i].y, lane_next(rows[i].x) * zn};
    }
    #pragma unroll
    for (int a = 0; a < ACT; ++a) {
      v2f q0 = (v2f){0.f, 0.f}, q1 = (v2f){0.f, 0.f};
      #pragma unroll
      for (int dy = 0; dy < 3; ++dy) {
        const float w0 = uload(&Wq[a * 18 + dy * 3 + 0]);
        const float w1 = uload(&Wq[a * 18 + dy * 3 + 1]);
        const float w2 = uload(&Wq[a * 18 + dy * 3 + 2]);
        q0 = cfma(w0, L[dy], q0);     q0 = cfma(w1, rows[dy], q0);
        q0 = cfma(w2, Rr[dy], q0);
        q1 = cfma(w0, L[dy + 1], q1); q1 = cfma(w1, rows[dy + 1], q1);
        q1 = cfma(w2, Rr[dy + 1], q1);
      }
      qr0[a] = q0; qr1[a] = q1;
      v0 = a ? cmax(v0, q0) : q0;
      v1 = a ? cmax(v1, q1) : q1;
    }
    tb[0][ty + 1][tx] = v0;
    bb[0][ty + 1][tx] = v1;
  }

  // pin VI weights: 2 consecutive weights per SGPR pair
  u64 wqp[36];
  #pragma unroll
  for (int p = 0; p < 36; ++p) {
    const int w0 = 2 * p, w1 = 2 * p + 1;
    const unsigned lo = (unsigned)__builtin_amdgcn_readfirstlane(
        __float_as_int(Wq[(w0 / 9) * 18 + 9 + (w0 % 9)]));
    const unsigned hi = (unsigned)__builtin_amdgcn_readfirstlane(
        __float_as_int(Wq[(w1 / 9) * 18 + 9 + (w1 % 9)]));
    wqp[p] = (u64)lo | ((u64)hi << 32);
  }
  __syncthreads();

  // ---- stage 3: 18 VI steps, trapezoid-predicated ----
  auto vi = [&](int s, int p) {
    const bool act = (wg == 0) ? (Rl <= 49 - s) : (Rl >= s + 1);
    if (act) {
      v2f rows[4];
      rows[0] = bb[p][ty][tx];
      rows[1] = v0;
      rows[2] = v1;
      rows[3] = tb[p][ty + 2][tx];
      v2f L[4], Rr[4];
      #pragma unroll
      for (int i = 0; i < 4; ++i) {
        L[i]  = (v2f){lane_prev(rows[i].y) * zp, rows[i].x};
        Rr[i] = (v2f){rows[i].y, lane_next(rows[i].x) * zn};
      }
      v2f m0, m1;
      #pragma unroll
      for (int a = 0; a < ACT; ++a) {
        v2f q0 = qr0[a], q1 = qr1[a];
        #pragma unroll
        for (int dy = 0; dy < 3; ++dy) {
          const int i0 = a * 9 + dy * 3 + 0;
          const int i1 = a * 9 + dy * 3 + 1;
          const int i2 = a * 9 + dy * 3 + 2;
          pkfma_s(q0, wqp[i0 >> 1], i0 & 1, L[dy]);
          pkfma_s(q0, wqp[i1 >> 1], i1 & 1, rows[dy]);
          pkfma_s(q0, wqp[i2 >> 1], i2 & 1, Rr[dy]);
          pkfma_s(q1, wqp[i0 >> 1], i0 & 1, L[dy + 1]);
          pkfma_s(q1, wqp[i1 >> 1], i1 & 1, rows[dy + 1]);
          pkfma_s(q1, wqp[i2 >> 1], i2 & 1, Rr[dy + 1]);
        }
        m0 = a ? cmax(m0, q0) : q0;
        m1 = a ? cmax(m1, q1) : q1;
      }
      v0 = m0; v1 = m1;
      tb[p ^ 1][ty + 1][tx] = v0;
      bb[p ^ 1][ty + 1][tx] = v1;
    }
    __syncthreads();
  };
  #pragma unroll 1
  for (int it = 0; it < 9; ++it) {
    vi(2 * it, 0);
    vi(2 * it + 1, 1);
  }

  // v19 -> v_s (garbage rows written too; reads stay in each WG's valid zone)
  *(v2f*)&v_s[Rl + 1][cc + 4] = v0;
  *(v2f*)&v_s[Rl + 2][cc + 4] = v1;
  __syncthreads();

  // ---- stage 4: queries split by row half; per-lane Wq loads (a not uniform) ----
  if (tid < 64 * ACT) {
    const int k = tid >> 3;
    const int a = tid & 7;
    const int qy = s12_s[k];
    const int qx = s12_s[64 + k];
    const bool mine = (wg == 0) ? (qy <= 31) : (qy >= 32);
    const int ly = mine ? (qy - B) : 25;   // safe in-bounds dummy when !mine
    float accq = 0.f;
    #pragma unroll
    for (int dy = 0; dy < 3; ++dy)
      #pragma unroll
      for (int dx = 0; dx < 3; ++dx) {
        const float w0 = Wq[a * 18 + dy * 3 + dx];
        const float w1 = Wq[a * 18 + 9 + dy * 3 + dx];
        accq += w0 * r_s[ly + dy][qx + dx + 3];
        accq += w1 * v_s[ly + dy][qx + dx + 3];
      }
    float m = accq;
    m = fmaxf(m, __shfl_xor(m, 1));
    m = fmaxf(m, __shfl_xor(m, 2));
    m = fmaxf(m, __shfl_xor(m, 4));
    const float e = __expf(accq - m);
    float s = e;
    s += __shfl_xor(s, 1);
    s += __shfl_xor(s, 2);
    s += __shfl_xor(s, 4);
    if (mine) out[tid] = e / s;
  }
}

extern "C" void kernel_launch(void* const* d_in, const int* in_sizes, int n_in,
                              void* d_out, int out_size, void* d_ws, size_t ws_size,
                              hipStream_t stream) {
  const float* X  = (const float*)d_in[0];
  const int*   S1 = (const int*)d_in[1];
  const int*   S2 = (const int*)d_in[2];
  const float* Wh = (const float*)d_in[3];
  const float* bh = (const float*)d_in[4];
  const float* Wr = (const float*)d_in[5];
  const float* Wq = (const float*)d_in[6];
  float* out = (float*)d_out;

  vin_kernel<<<2, NTHR, 0, stream>>>(X, S1, S2, Wh, bh, Wr, Wq, out);
}

// Round 11
// 90.626 us; speedup vs baseline: 1.7591x; 1.0105x over previous
//
#include <hip/hip_runtime.h>

// VIN, R11 = R10 (2-WG redundant-halo trapezoid) + VI-step latency restructure:
//  - phase-split: issue boundary ds_reads, run the 96 register-row pkfma first,
//    LDS-dependent 48 pkfma after -> post-barrier LDS latency hidden under issue
//  - max reduction as max3-fusable tree (28 -> ~16 instrs/step)
// Core (verified): 144 v_pk_fma_f32/step (SGPR-pair weights, op_sel dword
// select), DPP horizontal halo, b64 band-boundary LDS ping-pong, 1 barrier/step.
// >2 WGs is provably useless: interior strips of an 18-deep stencil need 52
// rows regardless -> per-CU band count (critical path) can't drop.

#define ACT 8
#define HID 150
#define STR 76
#define NB   26          // row-pair bands per WG
#define NTHR (NB * 32)   // 832 threads = 13 waves

typedef float v2f __attribute__((ext_vector_type(2)));
typedef unsigned long long u64;

__device__ __forceinline__ void pkfma_lo(v2f& acc, u64 wp, v2f x) {
  asm("v_pk_fma_f32 %0, %1, %2, %0 op_sel:[0,0,0] op_sel_hi:[0,1,1]"
      : "+v"(acc) : "s"(wp), "v"(x));
}
__device__ __forceinline__ void pkfma_hi(v2f& acc, u64 wp, v2f x) {
  asm("v_pk_fma_f32 %0, %1, %2, %0 op_sel:[1,0,0] op_sel_hi:[1,1,1]"
      : "+v"(acc) : "s"(wp), "v"(x));
}
__device__ __forceinline__ void pkfma_s(v2f& acc, u64 wp, int half, v2f x) {
  if (half == 0) pkfma_lo(acc, wp, x); else pkfma_hi(acc, wp, x);
}
__device__ __forceinline__ v2f cmax(v2f a, v2f b) {
  return (v2f){fmaxf(a.x, b.x), fmaxf(a.y, b.y)};
}
__device__ __forceinline__ v2f cfma(float w, v2f x, v2f acc) {
  acc.x = fmaf(w, x.x, acc.x);
  acc.y = fmaf(w, x.y, acc.y);
  return acc;
}
// max over 8 v2f, max3-fusable tree
__device__ __forceinline__ v2f max8(const v2f (&q)[ACT]) {
  v2f r;
  r.x = fmaxf(fmaxf(fmaxf(fmaxf(q[0].x, q[1].x), q[2].x),
                    fmaxf(fmaxf(q[3].x, q[4].x), q[5].x)),
              fmaxf(q[6].x, q[7].x));
  r.y = fmaxf(fmaxf(fmaxf(fmaxf(q[0].y, q[1].y), q[2].y),
                    fmaxf(fmaxf(q[3].y, q[4].y), q[5].y)),
              fmaxf(q[6].y, q[7].y));
  return r;
}
__device__ __forceinline__ float uload(const float* p) {  // wave-uniform only
  return __int_as_float(__builtin_amdgcn_readfirstlane(__float_as_int(*p)));
}
__device__ __forceinline__ float lane_prev(float x) {  // wave_shr:1, lane0->0
  return __int_as_float(
      __builtin_amdgcn_update_dpp(0, __float_as_int(x), 0x138, 0xF, 0xF, true));
}
__device__ __forceinline__ float lane_next(float x) {  // wave_shl:1, lane63->0
  return __int_as_float(
      __builtin_amdgcn_update_dpp(0, __float_as_int(x), 0x130, 0xF, 0xF, true));
}

__launch_bounds__(NTHR, 4)
__global__ void vin_kernel(const float* __restrict__ X,
                           const int*   __restrict__ S1,
                           const int*   __restrict__ S2,
                           const float* __restrict__ Wh,
                           const float* __restrict__ bh,
                           const float* __restrict__ Wr,
                           const float* __restrict__ Wq,
                           float*       __restrict__ out) {
  __shared__ float r_s[54][STR];       // local rows -1..52 (index = local+1)
  __shared__ float v_s[54][STR];       // v19, same indexing
  __shared__ v2f   tb[2][28][32];      // ping-pong: band top rows (+halo 0,27)
  __shared__ v2f   bb[2][28][32];      // ping-pong: band bottom rows
  __shared__ float weff_s[19];
  __shared__ int   s12_s[128];

  const int tid  = threadIdx.x;
  const int tx   = tid & 31;
  const int ty   = tid >> 5;           // 0..25
  const int lane = tid & 63;
  const float zp = (lane == 32) ? 0.f : 1.f;   // mid-wave band-crossing fixups
  const float zn = (lane == 31) ? 0.f : 1.f;
  const int Rl = ty << 1;              // local row of band top
  const int cc = tx << 1;
  const int wg = blockIdx.x;           // 0 or 1
  const int B  = wg * 12;              // global row base (WG1: rows 12..63)

  { // zero LDS (halos must be 0)
    const float4 z = make_float4(0.f, 0.f, 0.f, 0.f);
    float4* a = (float4*)&r_s[0][0];
    for (int i = tid; i < 54 * STR / 4; i += NTHR) a[i] = z;
    float4* b = (float4*)&v_s[0][0];
    for (int i = tid; i < 54 * STR / 4; i += NTHR) b[i] = z;
    float4* c = (float4*)&tb[0][0][0];
    for (int i = tid; i < 2 * 28 * 32 / 2; i += NTHR) c[i] = z;
    float4* d = (float4*)&bb[0][0][0];
    for (int i = tid; i < 2 * 28 * 32 / 2; i += NTHR) d[i] = z;
  }
  if (tid < 128) s12_s[tid] = (tid < 64) ? S1[tid] : S2[tid - 64];

  // weff contraction: 19 outputs x 32 lanes
  if (tid < 19 * 32) {
    const int t = tid >> 5, ln = tid & 31;
    float acc = 0.f;
    #pragma unroll
    for (int i = 0; i < 5; ++i) {
      const int h = ln + 32 * i;
      if (h < HID) acc += Wr[h] * (t < 18 ? Wh[h * 18 + t] : bh[h]);
    }
    acc += __shfl_xor(acc, 1);
    acc += __shfl_xor(acc, 2);
    acc += __shfl_xor(acc, 4);
    acc += __shfl_xor(acc, 8);
    acc += __shfl_xor(acc, 16);
    if (ln == 0) weff_s[t] = acc;
  }
  __syncthreads();

  // ---- stage 1: r EXACT on local rows 0..51 (X read at global rows) ----
  v2f ra, rb;
  {
    v2f xx[2][4];
    #pragma unroll
    for (int ch = 0; ch < 2; ++ch)
      #pragma unroll
      for (int dy = 0; dy < 4; ++dy) {
        const int g = B + Rl - 1 + dy;    // global row
        xx[ch][dy] = (g >= 0 && g < 64)
                   ? *(const v2f*)&X[ch * 4096 + g * 64 + cc]
                   : (v2f){0.f, 0.f};
      }
    float wl[18];
    #pragma unroll
    for (int t = 0; t < 18; ++t) wl[t] = uload(&weff_s[t]);
    const float beff = uload(&weff_s[18]);
    v2f a0 = (v2f){beff, beff}, a1 = a0;
    #pragma unroll
    for (int ch = 0; ch < 2; ++ch) {
      v2f L[4], Rr[4];
      #pragma unroll
      for (int i = 0; i < 4; ++i) {
        L[i]  = (v2f){lane_prev(xx[ch][i].y) * zp, xx[ch][i].x};
        Rr[i] = (v2f){xx[ch][i].y, lane_next(xx[ch][i].x) * zn};
      }
      #pragma unroll
      for (int dy = 0; dy < 3; ++dy) {
        const float w0 = wl[ch * 9 + dy * 3 + 0];
        const float w1 = wl[ch * 9 + dy * 3 + 1];
        const float w2 = wl[ch * 9 + dy * 3 + 2];
        a0 = cfma(w0, L[dy], a0);     a0 = cfma(w1, xx[ch][dy], a0);
        a0 = cfma(w2, Rr[dy], a0);
        a1 = cfma(w0, L[dy + 1], a1); a1 = cfma(w1, xx[ch][dy + 1], a1);
        a1 = cfma(w2, Rr[dy + 1], a1);
      }
    }
    *(v2f*)&r_s[Rl + 1][cc + 4] = a0;
    *(v2f*)&r_s[Rl + 2][cc + 4] = a1;
    ra = a0; rb = a1;
  }
  __syncthreads();

  // ---- stage 2: qr (iteration-invariant); v1 = max_a qr ----
  v2f qr0[ACT], qr1[ACT], v0, v1;
  {
    v2f rows[4];
    rows[0] = *(const v2f*)&r_s[Rl][cc + 4];
    rows[1] = ra;
    rows[2] = rb;
    rows[3] = *(const v2f*)&r_s[Rl + 3][cc + 4];
    v2f L[4], Rr[4];
    #pragma unroll
    for (int i = 0; i < 4; ++i) {
      L[i]  = (v2f){lane_prev(rows[i].y) * zp, rows[i].x};
      Rr[i] = (v2f){rows[i].y, lane_next(rows[i].x) * zn};
    }
    #pragma unroll
    for (int a = 0; a < ACT; ++a) {
      v2f q0 = (v2f){0.f, 0.f}, q1 = (v2f){0.f, 0.f};
      #pragma unroll
      for (int dy = 0; dy < 3; ++dy) {
        const float w0 = uload(&Wq[a * 18 + dy * 3 + 0]);
        const float w1 = uload(&Wq[a * 18 + dy * 3 + 1]);
        const float w2 = uload(&Wq[a * 18 + dy * 3 + 2]);
        q0 = cfma(w0, L[dy], q0);     q0 = cfma(w1, rows[dy], q0);
        q0 = cfma(w2, Rr[dy], q0);
        q1 = cfma(w0, L[dy + 1], q1); q1 = cfma(w1, rows[dy + 1], q1);
        q1 = cfma(w2, Rr[dy + 1], q1);
      }
      qr0[a] = q0; qr1[a] = q1;
      v0 = a ? cmax(v0, q0) : q0;
      v1 = a ? cmax(v1, q1) : q1;
    }
    tb[0][ty + 1][tx] = v0;
    bb[0][ty + 1][tx] = v1;
  }

  // pin VI weights: 2 consecutive weights per SGPR pair
  u64 wqp[36];
  #pragma unroll
  for (int p = 0; p < 36; ++p) {
    const int w0 = 2 * p, w1 = 2 * p + 1;
    const unsigned lo = (unsigned)__builtin_amdgcn_readfirstlane(
        __float_as_int(Wq[(w0 / 9) * 18 + 9 + (w0 % 9)]));
    const unsigned hi = (unsigned)__builtin_amdgcn_readfirstlane(
        __float_as_int(Wq[(w1 / 9) * 18 + 9 + (w1 % 9)]));
    wqp[p] = (u64)lo | ((u64)hi << 32);
  }
  __syncthreads();

  // ---- stage 3: 18 VI steps, trapezoid-predicated, phase-split ----
  auto vi = [&](int s, int p) {
    const bool act = (wg == 0) ? (Rl <= 49 - s) : (Rl >= s + 1);
    if (act) {
      // issue boundary reads first; consume them only in phase 2
      const v2f r0 = bb[p][ty][tx];        // row 2ty-1 (halo row 0 = zeros)
      const v2f r3 = tb[p][ty + 2][tx];    // row 2ty+2 (halo row 27 = zeros)

      // mid-row packs (registers only)
      v2f L1 = (v2f){lane_prev(v0.y) * zp, v0.x};
      v2f R1 = (v2f){v0.y, lane_next(v0.x) * zn};
      v2f L2 = (v2f){lane_prev(v1.y) * zp, v1.x};
      v2f R2 = (v2f){v1.y, lane_next(v1.x) * zn};

      v2f qq0[ACT], qq1[ACT];
      // phase 1: all taps on register rows v0 (weight-row 1 for q0, 0 for q1)
      // and v1 (weight-row 2 for q0, 1 for q1) -> 96 pkfma, no LDS dependence
      #pragma unroll
      for (int a = 0; a < ACT; ++a) {
        v2f q0 = qr0[a], q1 = qr1[a];
        const int i10 = a * 9 + 3, i11 = a * 9 + 4, i12 = a * 9 + 5;
        const int i20 = a * 9 + 6, i21 = a * 9 + 7, i22 = a * 9 + 8;
        const int i00 = a * 9 + 0, i01 = a * 9 + 1, i02 = a * 9 + 2;
        // q0: weight-row1 x v0, weight-row2 x v1
        pkfma_s(q0, wqp[i10 >> 1], i10 & 1, L1);
        pkfma_s(q0, wqp[i11 >> 1], i11 & 1, v0);
        pkfma_s(q0, wqp[i12 >> 1], i12 & 1, R1);
        pkfma_s(q0, wqp[i20 >> 1], i20 & 1, L2);
        pkfma_s(q0, wqp[i21 >> 1], i21 & 1, v1);
        pkfma_s(q0, wqp[i22 >> 1], i22 & 1, R2);
        // q1: weight-row0 x v0, weight-row1 x v1
        pkfma_s(q1, wqp[i00 >> 1], i00 & 1, L1);
        pkfma_s(q1, wqp[i01 >> 1], i01 & 1, v0);
        pkfma_s(q1, wqp[i02 >> 1], i02 & 1, R1);
        pkfma_s(q1, wqp[i10 >> 1], i10 & 1, L2);
        pkfma_s(q1, wqp[i11 >> 1], i11 & 1, v1);
        pkfma_s(q1, wqp[i12 >> 1], i12 & 1, R2);
        qq0[a] = q0; qq1[a] = q1;
      }

      // phase 2: LDS-row packs + remaining 48 pkfma
      v2f L0 = (v2f){lane_prev(r0.y) * zp, r0.x};
      v2f R0 = (v2f){r0.y, lane_next(r0.x) * zn};
      v2f L3 = (v2f){lane_prev(r3.y) * zp, r3.x};
      v2f R3 = (v2f){r3.y, lane_next(r3.x) * zn};
      #pragma unroll
      for (int a = 0; a < ACT; ++a) {
        const int i00 = a * 9 + 0, i01 = a * 9 + 1, i02 = a * 9 + 2;
        const int i20 = a * 9 + 6, i21 = a * 9 + 7, i22 = a * 9 + 8;
        pkfma_s(qq0[a], wqp[i00 >> 1], i00 & 1, L0);   // q0: weight-row0 x r0
        pkfma_s(qq0[a], wqp[i01 >> 1], i01 & 1, r0);
        pkfma_s(qq0[a], wqp[i02 >> 1], i02 & 1, R0);
        pkfma_s(qq1[a], wqp[i20 >> 1], i20 & 1, L3);   // q1: weight-row2 x r3
        pkfma_s(qq1[a], wqp[i21 >> 1], i21 & 1, r3);
        pkfma_s(qq1[a], wqp[i22 >> 1], i22 & 1, R3);
      }
      v0 = max8(qq0);
      v1 = max8(qq1);
      tb[p ^ 1][ty + 1][tx] = v0;
      bb[p ^ 1][ty + 1][tx] = v1;
    }
    __syncthreads();
  };
  #pragma unroll 1
  for (int it = 0; it < 9; ++it) {
    vi(2 * it, 0);
    vi(2 * it + 1, 1);
  }

  // v19 -> v_s (garbage rows written too; reads stay in each WG's valid zone)
  *(v2f*)&v_s[Rl + 1][cc + 4] = v0;
  *(v2f*)&v_s[Rl + 2][cc + 4] = v1;
  __syncthreads();

  // ---- stage 4: queries split by row half; per-lane Wq loads (a not uniform) ----
  if (tid < 64 * ACT) {
    const int k = tid >> 3;
    const int a = tid & 7;
    const int qy = s12_s[k];
    const int qx = s12_s[64 + k];
    const bool mine = (wg == 0) ? (qy <= 31) : (qy >= 32);
    const int ly = mine ? (qy - B) : 25;   // safe in-bounds dummy when !mine
    float accq = 0.f;
    #pragma unroll
    for (int dy = 0; dy < 3; ++dy)
      #pragma unroll
      for (int dx = 0; dx < 3; ++dx) {
        const float w0 = Wq[a * 18 + dy * 3 + dx];
        const float w1 = Wq[a * 18 + 9 + dy * 3 + dx];
        accq += w0 * r_s[ly + dy][qx + dx + 3];
        accq += w1 * v_s[ly + dy][qx + dx + 3];
      }
    float m = accq;
    m = fmaxf(m, __shfl_xor(m, 1));
    m = fmaxf(m, __shfl_xor(m, 2));
    m = fmaxf(m, __shfl_xor(m, 4));
    const float e = __expf(accq - m);
    float s = e;
    s += __shfl_xor(s, 1);
    s += __shfl_xor(s, 2);
    s += __shfl_xor(s, 4);
    if (mine) out[tid] = e / s;
  }
}

extern "C" void kernel_launch(void* const* d_in, const int* in_sizes, int n_in,
                              void* d_out, int out_size, void* d_ws, size_t ws_size,
                              hipStream_t stream) {
  const float* X  = (const float*)d_in[0];
  const int*   S1 = (const int*)d_in[1];
  const int*   S2 = (const int*)d_in[2];
  const float* Wh = (const float*)d_in[3];
  const float* bh = (const float*)d_in[4];
  const float* Wr = (const float*)d_in[5];
  const float* Wq = (const float*)d_in[6];
  float* out = (float*)d_out;

  vin_kernel<<<2, NTHR, 0, stream>>>(X, S1, S2, Wh, bh, Wr, Wq, out);
}